// Round 1
// baseline (273.223 us; speedup 1.0000x reference)
//
#include <hip/hip_runtime.h>

#define N_NODES 50000
#define N_EDGES 800000
#define F 64

// ---------------------------------------------------------------------------
// GCNConv improved=True:
//   deg[n] = 2.0 + #incoming edges ; dinv = deg^-0.5
//   agg[dst] += dinv[src]*dinv[dst]*x[src]  (+ self loop 2*dinv[n]^2 * x[n])
//   out = log_softmax(relu(agg @ W + b), axis=1)
// We aggregate x BEFORE the weight transform ( (A x) W == A (x W) ) so the
// only scratch needed is deg/dinv (200 KB in d_ws); d_out doubles as the
// aggregation buffer and is fully re-initialized every call.
// ---------------------------------------------------------------------------

__global__ void k_init_deg(float* __restrict__ deg) {
    int i = blockIdx.x * blockDim.x + threadIdx.x;
    if (i < N_NODES) deg[i] = 2.0f;   // self-loop weight
}

__global__ void k_count(const int* __restrict__ dst, float* __restrict__ deg) {
    int e = blockIdx.x * blockDim.x + threadIdx.x;
    if (e < N_EDGES) atomicAdd(&deg[dst[e]], 1.0f);
}

__global__ void k_dinv(float* __restrict__ deg) {
    int i = blockIdx.x * blockDim.x + threadIdx.x;
    if (i < N_NODES) deg[i] = rsqrtf(deg[i]);   // deg >= 2 always
}

// agg[n][f] = 2 * dinv[n]^2 * x[n][f]   -- full overwrite of d_out (no memset)
__global__ void k_selfinit(const float* __restrict__ x,
                           const float* __restrict__ dinv,
                           float* __restrict__ agg) {
    int t = blockIdx.x * blockDim.x + threadIdx.x;   // over N*16 float4s
    if (t >= N_NODES * (F / 4)) return;
    int n = t >> 4;
    float d = dinv[n];
    float c = 2.0f * d * d;
    float4 v = reinterpret_cast<const float4*>(x)[t];
    float4 o;
    o.x = c * v.x; o.y = c * v.y; o.z = c * v.z; o.w = c * v.w;
    reinterpret_cast<float4*>(agg)[t] = o;
}

// one 64-lane wave per edge; lane = feature
__global__ __launch_bounds__(256) void k_scatter(const int* __restrict__ src,
                                                 const int* __restrict__ dst,
                                                 const float* __restrict__ x,
                                                 const float* __restrict__ dinv,
                                                 float* __restrict__ agg) {
    int wave = (blockIdx.x * blockDim.x + threadIdx.x) >> 6;
    int lane = threadIdx.x & 63;
    if (wave >= N_EDGES) return;
    int s = src[wave];
    int d = dst[wave];
    float c = dinv[s] * dinv[d];
    float v = x[s * F + lane];               // coalesced 256B row read
    atomicAdd(&agg[d * F + lane], c * v);    // device-scope f32 atomic
}

// per-node epilogue: y = row @ W + b ; relu ; log_softmax over 64 features.
// 4 nodes per 256-thread block, one wave per node, lane = output feature.
__global__ __launch_bounds__(256) void k_final(const float* __restrict__ W,
                                               const float* __restrict__ b,
                                               float* __restrict__ out) {
    __shared__ float sW[F * F];
    __shared__ float srow[4][F];
    int t = threadIdx.x;
    for (int i = t; i < F * F; i += 256) sW[i] = W[i];
    int wid  = t >> 6;
    int lane = t & 63;
    int n = blockIdx.x * 4 + wid;            // 12500 * 4 == 50000 exactly
    float rv = out[n * F + lane];
    srow[wid][lane] = rv;
    __syncthreads();

    float y = b[lane];
#pragma unroll
    for (int k = 0; k < F; ++k)
        y = fmaf(srow[wid][k], sW[k * F + lane], y);
    y = fmaxf(y, 0.0f);

    // wave-wide (64-lane) max and sum reductions
    float m = y;
#pragma unroll
    for (int off = 32; off > 0; off >>= 1)
        m = fmaxf(m, __shfl_xor(m, off));
    float ex = __expf(y - m);
    float ssum = ex;
#pragma unroll
    for (int off = 32; off > 0; off >>= 1)
        ssum += __shfl_xor(ssum, off);

    out[n * F + lane] = y - m - __logf(ssum);
}

extern "C" void kernel_launch(void* const* d_in, const int* in_sizes, int n_in,
                              void* d_out, int out_size, void* d_ws, size_t ws_size,
                              hipStream_t stream) {
    const float* x    = (const float*)d_in[0];
    const int*   eidx = (const int*)d_in[1];   // [2][E]: row0 = src, row1 = dst
    const float* W    = (const float*)d_in[2];
    const float* b    = (const float*)d_in[3];
    const int* src = eidx;
    const int* dst = eidx + N_EDGES;

    float* deg = (float*)d_ws;                 // 50000 floats, becomes dinv
    float* agg = (float*)d_out;                // aggregation buffer == output

    k_init_deg<<<(N_NODES + 255) / 256, 256, 0, stream>>>(deg);
    k_count<<<(N_EDGES + 255) / 256, 256, 0, stream>>>(dst, deg);
    k_dinv<<<(N_NODES + 255) / 256, 256, 0, stream>>>(deg);
    k_selfinit<<<(N_NODES * (F / 4) + 255) / 256, 256, 0, stream>>>(x, deg, agg);

    int scatter_blocks = (N_EDGES * 64 + 255) / 256;   // 200000
    k_scatter<<<scatter_blocks, 256, 0, stream>>>(src, dst, x, deg, agg);

    k_final<<<N_NODES / 4, 256, 0, stream>>>(W, b, agg);
}